// Round 2
// baseline (15653.032 us; speedup 1.0000x reference)
//
#include <hip/hip_runtime.h>
#include <math.h>

// ---------------- problem constants ----------------
#define NB    8
#define NPTS  100000
#define NCLS  18
#define ND    128
#define KFPS  2048
#define KTOP  256

// ---------------- FPS config ----------------
#define FWGS       32                 // workgroups per batch
#define FTHR       256                // threads per WG
#define FBTHREADS  (FWGS*FTHR)        // 8192 threads per batch
#define PPT        13                 // points per thread (13*8192 >= 100000)
#define NPART      128                // per-wave partial records per batch
#define TAG_SHIFT  49
#define KEY_MASK   ((1ull<<TAG_SHIFT)-1)
#define IDX_MASK   0x1FFFFull
#define INVALID_REC (~0ull)           // tag 0x7FFF: never matches any live tag

static_assert(PPT * FBTHREADS >= NPTS, "coverage");

// ---------------- out layout (float elements) ----------------
#define OUT_PTS    0          // 8*256*3    = 6144
#define OUT_FEATS  6144       // 8*256*128  = 262144
#define OUT_INDS   268288     // 8*256      = 2048
#define OUT_CROSS  270336     // 8*2048*128 = 2097152  (total 2367488)
#define OUT_SCORES OUT_CROSS  // temp: 800000 floats scratch inside region 3

// ---------------- ws layout (bytes) ----------------
#define WS_PARTIALS 0                       // NB*2*NPART*8 = 16384
#define WS_CROSS    16384                   // NB*KFPS*4    = 65536
#define WS_SORTI    (16384+65536)           // NB*KTOP*4    = 8192  (end 90112)

// ============================================================
// Kernel 0: init partial-record slots (runs before k_fps every call)
// ============================================================
__global__ void k_init(unsigned long long* __restrict__ partials) {
  int id = blockIdx.x * 256 + threadIdx.x;
  if (id < NB * 2 * NPART) partials[id] = INVALID_REC;
}

// ============================================================
// Kernel 1: max_scores = sigmoid(max_c cls) * sigmoid(centerness)
// ============================================================
__global__ void k_scores(const float* __restrict__ cent,
                         const float* __restrict__ cls,
                         float* __restrict__ scores) {
  int gid = blockIdx.x * blockDim.x + threadIdx.x;
  if (gid >= NB * NPTS) return;
  const float* c = cls + (size_t)gid * NCLS;
  float m = c[0];
  #pragma unroll
  for (int i = 1; i < NCLS; ++i) m = fmaxf(m, c[i]);
  double sm = 1.0 / (1.0 + exp(-(double)m));
  double sc = 1.0 / (1.0 + exp(-(double)cent[gid]));
  scores[gid] = __fmul_rn((float)sm, (float)sc);
}

// ============================================================
// Kernel 2: per-batch exact top-256 (value desc, idx asc), output sorted idx
// ============================================================
__global__ __launch_bounds__(1024) void k_topk(const float* __restrict__ scores,
                                               int* __restrict__ sorti_ws,
                                               float* __restrict__ out_inds) {
  __shared__ unsigned hist[2048];
  __shared__ int candG[256];
  __shared__ int candE[512];
  __shared__ unsigned s_cg, s_ce, s_bin, s_rank;

  int b = blockIdx.x;
  int tid = threadIdx.x;
  const float* sb = scores + (size_t)b * NPTS;

  unsigned prefix = 0, pmask = 0;
  int r = KTOP;
  for (int pass = 0; pass < 3; ++pass) {
    int shift = (pass == 0) ? 21 : (pass == 1) ? 10 : 0;
    int bins  = (pass < 2) ? 2048 : 1024;
    for (int i = tid; i < bins; i += 1024) hist[i] = 0;
    __syncthreads();
    for (int n = tid; n < NPTS; n += 1024) {
      unsigned k = __float_as_uint(sb[n]);
      if ((k & pmask) == prefix) atomicAdd(&hist[(k >> shift) & (bins - 1)], 1u);
    }
    __syncthreads();
    if (tid == 0) {
      unsigned c = 0; int bin = bins - 1;
      for (; bin > 0; --bin) { unsigned h = hist[bin]; if (c + h >= (unsigned)r) break; c += h; }
      s_bin = (unsigned)bin; s_rank = (unsigned)r - c;
    }
    __syncthreads();
    prefix |= s_bin << shift;
    pmask  |= (unsigned)(bins - 1) << shift;
    r = (int)s_rank;
    __syncthreads();
  }
  unsigned T = prefix;     // exact 32-bit threshold key
  int need = r;            // how many ==T to take (lowest indices)
  int nG = KTOP - need;    // count of keys > T

  if (tid == 0) { s_cg = 0; s_ce = 0; }
  __syncthreads();
  for (int n = tid; n < NPTS; n += 1024) {
    unsigned k = __float_as_uint(sb[n]);
    if (k > T)       { unsigned p = atomicAdd(&s_cg, 1u); if (p < 256) candG[p] = n; }
    else if (k == T) { unsigned p = atomicAdd(&s_ce, 1u); if (p < 512) candE[p] = n; }
  }
  __syncthreads();
  unsigned ce = s_ce;
  for (int i = tid; i < 512; i += 1024) if (i >= (int)ce) candE[i] = 0x7FFFFFFF;
  __syncthreads();
  // bitonic sort candE ascending (n=512)
  for (int k2 = 2; k2 <= 512; k2 <<= 1)
    for (int j = k2 >> 1; j >= 1; j >>= 1) {
      if (tid < 512) {
        int i = tid, p = i ^ j;
        if (p > i) {
          int a = candE[i], bb = candE[p];
          bool up = ((i & k2) == 0);
          if ((a > bb) == up) { candE[i] = bb; candE[p] = a; }
        }
      }
      __syncthreads();
    }
  int* arr = (int*)hist;   // reuse
  if (tid < KTOP) arr[tid] = (tid < nG) ? candG[tid] : candE[tid - nG];
  __syncthreads();
  // bitonic sort final 256 ascending
  for (int k2 = 2; k2 <= 256; k2 <<= 1)
    for (int j = k2 >> 1; j >= 1; j >>= 1) {
      if (tid < 256) {
        int i = tid, p = i ^ j;
        if (p > i) {
          int a = arr[i], bb = arr[p];
          bool up = ((i & k2) == 0);
          if ((a > bb) == up) { arr[i] = bb; arr[p] = a; }
        }
      }
      __syncthreads();
    }
  if (tid < KTOP) {
    sorti_ws[b * KTOP + tid] = arr[tid];
    out_inds[b * KTOP + tid] = (float)arr[tid];
  }
}

// ============================================================
// Kernel 3: furthest point sampling, bit-exact f32, register-resident.
// 32 WGs/batch, per-wave tagged partial records, ping-pong slot banks.
// Tags are t+1 (1..2047): 0x0000 (zeros), 0x5555 (0xAA poison) and
// 0x7FFF (our reset) can never match a live tag.
// ============================================================
__global__ __launch_bounds__(FTHR) void k_fps(const float* __restrict__ points,
                                              unsigned long long* __restrict__ partials,
                                              int* __restrict__ cross_inds) {
  int b    = blockIdx.x & 7;     // XCD-friendly: batch b's WGs round-robin to same XCD
  int wg   = blockIdx.x >> 3;    // 0..31
  int tid  = threadIdx.x;
  int lane = tid & 63;
  int wave = tid >> 6;           // 0..3
  int gthr = wg * FTHR + tid;    // 0..8191 within batch
  int slot = wg * 4 + wave;      // 0..127

  const float* pb = points + (size_t)b * NPTS * 3;
  unsigned long long* part = partials + (size_t)b * 2 * NPART;

  float px[PPT], py[PPT], pz[PPT], dd[PPT];
  #pragma unroll
  for (int i = 0; i < PPT; ++i) {
    int n = gthr + i * FBTHREADS;
    bool v = (n < NPTS);
    px[i] = v ? pb[3 * n + 0] : 0.f;
    py[i] = v ? pb[3 * n + 1] : 0.f;
    pz[i] = v ? pb[3 * n + 2] : 0.f;
    dd[i] = 1e10f;
  }
  if (blockIdx.x < 8 && tid == 0) cross_inds[b * KFPS] = 0;

  int w = 0;
  for (int t = 0; t < KFPS - 1; ++t) {
    float wx = pb[3 * w + 0];
    float wy = pb[3 * w + 1];
    float wz = pb[3 * w + 2];

    // exact f32 update: d = ((dx*dx + dy*dy) + dz*dz), dist = min(dist, d)
    float bestv = -1.f; int besti = 0x1FFFF;
    #pragma unroll
    for (int i = 0; i < PPT; ++i) {
      int n = gthr + i * FBTHREADS;
      float dx = __fsub_rn(px[i], wx);
      float dy = __fsub_rn(py[i], wy);
      float dz = __fsub_rn(pz[i], wz);
      float s  = __fadd_rn(__fadd_rn(__fmul_rn(dx, dx), __fmul_rn(dy, dy)), __fmul_rn(dz, dz));
      float nd = fminf(dd[i], s);
      dd[i] = nd;
      bool upd = (n < NPTS) && (nd > bestv);   // strict > keeps lowest index on ties
      bestv = upd ? nd : bestv;
      besti = upd ? n : besti;
    }
    // pack (value, ~idx): max => max value, then min index
    unsigned long long key = (bestv >= 0.f)
      ? (((unsigned long long)__float_as_uint(bestv) << 17) |
         (unsigned long long)(0x1FFFFu ^ (unsigned)besti))
      : 0ull;
    #pragma unroll
    for (int off = 32; off >= 1; off >>= 1) {
      unsigned long long o = __shfl_xor(key, off);
      if (o > key) key = o;
    }
    // publish this wave's record (tagged, self-contained, relaxed agent atomic)
    unsigned tag = (unsigned)t + 1u;
    unsigned long long rec = ((unsigned long long)tag << TAG_SHIFT) | key;
    unsigned long long* bank = part + (size_t)(t & 1) * NPART;
    if (lane == 0)
      __hip_atomic_store(&bank[slot], rec, __ATOMIC_RELAXED, __HIP_MEMORY_SCOPE_AGENT);

    // poll all 128 records of this batch (lanes cover 2 each)
    unsigned long long r0, r1;
    int spins = 0;
    for (;;) {
      r0 = __hip_atomic_load(&bank[lane],      __ATOMIC_RELAXED, __HIP_MEMORY_SCOPE_AGENT);
      r1 = __hip_atomic_load(&bank[64 + lane], __ATOMIC_RELAXED, __HIP_MEMORY_SCOPE_AGENT);
      bool ok = ((unsigned)(r0 >> TAG_SHIFT) == tag) &&
                ((unsigned)(r1 >> TAG_SHIFT) == tag);
      if (__all((int)ok)) break;
      if (++spins > (1 << 16)) break;          // safety: bounded worst case
      __builtin_amdgcn_s_sleep(1);
    }
    unsigned long long k0 = r0 & KEY_MASK;
    unsigned long long k1 = r1 & KEY_MASK;
    unsigned long long kk = (k0 > k1) ? k0 : k1;
    #pragma unroll
    for (int off = 32; off >= 1; off >>= 1) {
      unsigned long long o = __shfl_xor(kk, off);
      if (o > kk) kk = o;
    }
    w = (int)(0x1FFFFu ^ (unsigned)(kk & IDX_MASK));
    if (w >= NPTS) w = 0;                      // safety: never OOB, even on failure
    if (blockIdx.x < 8 && tid == 0) cross_inds[b * KFPS + t + 1] = w;
  }
}

// ============================================================
// Kernel 4: gathers (feats_sel, pts_sel, cross_features) + partial-slot reset
// ============================================================
#define GF4 ((NB * (KTOP + KFPS)) * (ND / 4))   // 589824 float4 gathers
#define GPTS (NB * KTOP * 3)                    // 6144
#define GRST (NB * 2 * NPART)                   // 2048 u64 resets

__global__ void k_gather(const float* __restrict__ pts,
                         const float* __restrict__ feat,
                         const int* __restrict__ sorti,
                         const int* __restrict__ crossi,
                         unsigned long long* __restrict__ partials,
                         float* __restrict__ out) {
  int id = blockIdx.x * 256 + threadIdx.x;
  if (id < GF4) {
    int row = id >> 5, c4 = id & 31;
    int b, s; float* dst;
    if (row < NB * KTOP) {
      b = row >> 8;
      s = sorti[row];
      dst = out + OUT_FEATS + (size_t)row * ND;
    } else {
      int r2 = row - NB * KTOP;
      b = r2 >> 11;
      s = crossi[r2];
      dst = out + OUT_CROSS + (size_t)r2 * ND;
    }
    if (s < 0 || s >= NPTS) s = 0;             // safety
    float4 v = ((const float4*)(feat + ((size_t)b * NPTS + (size_t)s) * ND))[c4];
    ((float4*)dst)[c4] = v;
  } else if (id < GF4 + GPTS) {
    int q = id - GF4;
    int row = q / 3, d = q - row * 3;
    int b = row >> 8;
    int s = sorti[row];
    if (s < 0 || s >= NPTS) s = 0;             // safety
    out[OUT_PTS + q] = pts[((size_t)b * NPTS + (size_t)s) * 3 + d];
  } else if (id < GF4 + GPTS + GRST) {
    partials[id - GF4 - GPTS] = INVALID_REC;    // tag 0x7FFF: never matches any tag
  }
}

// ============================================================
extern "C" void kernel_launch(void* const* d_in, const int* in_sizes, int n_in,
                              void* d_out, int out_size, void* d_ws, size_t ws_size,
                              hipStream_t stream) {
  const float* cent = (const float*)d_in[0];
  const float* cls  = (const float*)d_in[1];
  const float* pts  = (const float*)d_in[2];
  const float* feat = (const float*)d_in[3];
  float* out = (float*)d_out;

  unsigned long long* partials = (unsigned long long*)d_ws;
  int* cross_ws = (int*)((char*)d_ws + WS_CROSS);
  int* sorti_ws = (int*)((char*)d_ws + WS_SORTI);
  float* scores = out + OUT_SCORES;   // scratch inside out region 3 (overwritten later)

  hipLaunchKernelGGL(k_init, dim3((NB * 2 * NPART + 255) / 256), dim3(256), 0, stream,
                     partials);
  hipLaunchKernelGGL(k_scores, dim3((NB * NPTS + 255) / 256), dim3(256), 0, stream,
                     cent, cls, scores);
  hipLaunchKernelGGL(k_topk, dim3(NB), dim3(1024), 0, stream,
                     scores, sorti_ws, out + OUT_INDS);
  hipLaunchKernelGGL(k_fps, dim3(NB * FWGS), dim3(FTHR), 0, stream,
                     pts, partials, cross_ws);
  int gtot = GF4 + GPTS + GRST;
  hipLaunchKernelGGL(k_gather, dim3((gtot + 255) / 256), dim3(256), 0, stream,
                     pts, feat, sorti_ws, cross_ws, partials, out);
}

// Round 5
// 4561.524 us; speedup vs baseline: 3.4315x; 3.4315x over previous
//
#include <hip/hip_runtime.h>
#include <math.h>

// ---------------- problem constants ----------------
#define NB    8
#define NPTS  100000
#define NCLS  18
#define ND    128
#define KFPS  2048
#define KTOP  256

// ---------------- FPS config ----------------
#define FWGS       32                 // workgroups per batch
#define FTHR       256                // threads per WG
#define FBTHREADS  (FWGS*FTHR)        // 8192 threads per batch
#define PPT        13                 // points per thread (13*8192 >= 100000)
#define NSLOT      32                 // one record per WG per batch
#define RSTRIDE    64                 // u64s per record slot (512 B) -> channel spread
#define TAG_SHIFT  49
#define KEY_MASK   ((1ull<<TAG_SHIFT)-1)
#define IDX_MASK   0x1FFFFull
#define INVALID_REC (~0ull)           // tag 0x7FFF: never matches any live tag (1..2047)

#define PART_U64   (NB * 2 * NSLOT * RSTRIDE)   // 32768 u64 = 256 KB

static_assert(PPT * FBTHREADS >= NPTS, "coverage");

// ---------------- out layout (float elements), total 2367488 ----------------
#define OUT_PTS    0          // 8*256*3    = 6144
#define OUT_FEATS  6144       // 8*256*128  = 262144
#define OUT_INDS   268288     // 8*256      = 2048
#define OUT_CROSS  270336     // 8*2048*128 = 2097152
// scratch INSIDE region 3 (overwritten by k_gather at the end):
#define OUT_SCORES OUT_CROSS              // 800000 floats
#define OUT_PART   (OUT_CROSS + 800000)   // 65536 floats (= 32768 u64, 8B-aligned)
static_assert((OUT_PART % 2) == 0, "u64 alignment");
static_assert(OUT_PART + PART_U64 * 2 <= OUT_CROSS + 2097152, "fits in region 3");

// ---------------- ws layout (bytes) — EXACTLY round-2's proven 90112 ----------------
#define WS_CROSS    16384                   // NB*KFPS*4 = 65536
#define WS_SORTI    (16384+65536)           // NB*KTOP*4 = 8192   (end 90112)

// ============================================================
// Kernel 0: init partial-record slots (runs before k_fps every call)
// ============================================================
__global__ void k_init(unsigned long long* __restrict__ partials) {
  int id = blockIdx.x * 256 + threadIdx.x;
  if (id < PART_U64) partials[id] = INVALID_REC;
}

// ============================================================
// Kernel 1: max_scores = sigmoid(max_c cls) * sigmoid(centerness)
// ============================================================
__global__ void k_scores(const float* __restrict__ cent,
                         const float* __restrict__ cls,
                         float* __restrict__ scores) {
  int gid = blockIdx.x * blockDim.x + threadIdx.x;
  if (gid >= NB * NPTS) return;
  const float* c = cls + (size_t)gid * NCLS;
  float m = c[0];
  #pragma unroll
  for (int i = 1; i < NCLS; ++i) m = fmaxf(m, c[i]);
  double sm = 1.0 / (1.0 + exp(-(double)m));
  double sc = 1.0 / (1.0 + exp(-(double)cent[gid]));
  scores[gid] = __fmul_rn((float)sm, (float)sc);
}

// ============================================================
// Kernel 2: per-batch exact top-256 (value desc, idx asc), output sorted idx
// ============================================================
__global__ __launch_bounds__(1024) void k_topk(const float* __restrict__ scores,
                                               int* __restrict__ sorti_ws,
                                               float* __restrict__ out_inds) {
  __shared__ unsigned hist[2048];
  __shared__ int candG[256];
  __shared__ int candE[512];
  __shared__ unsigned s_cg, s_ce, s_bin, s_rank;

  int b = blockIdx.x;
  int tid = threadIdx.x;
  const float* sb = scores + (size_t)b * NPTS;

  unsigned prefix = 0, pmask = 0;
  int r = KTOP;
  for (int pass = 0; pass < 3; ++pass) {
    int shift = (pass == 0) ? 21 : (pass == 1) ? 10 : 0;
    int bins  = (pass < 2) ? 2048 : 1024;
    for (int i = tid; i < bins; i += 1024) hist[i] = 0;
    __syncthreads();
    for (int n = tid; n < NPTS; n += 1024) {
      unsigned k = __float_as_uint(sb[n]);
      if ((k & pmask) == prefix) atomicAdd(&hist[(k >> shift) & (bins - 1)], 1u);
    }
    __syncthreads();
    if (tid == 0) {
      unsigned c = 0; int bin = bins - 1;
      for (; bin > 0; --bin) { unsigned h = hist[bin]; if (c + h >= (unsigned)r) break; c += h; }
      s_bin = (unsigned)bin; s_rank = (unsigned)r - c;
    }
    __syncthreads();
    prefix |= s_bin << shift;
    pmask  |= (unsigned)(bins - 1) << shift;
    r = (int)s_rank;
    __syncthreads();
  }
  unsigned T = prefix;     // exact 32-bit threshold key
  int need = r;            // how many ==T to take (lowest indices)
  int nG = KTOP - need;    // count of keys > T

  if (tid == 0) { s_cg = 0; s_ce = 0; }
  __syncthreads();
  for (int n = tid; n < NPTS; n += 1024) {
    unsigned k = __float_as_uint(sb[n]);
    if (k > T)       { unsigned p = atomicAdd(&s_cg, 1u); if (p < 256) candG[p] = n; }
    else if (k == T) { unsigned p = atomicAdd(&s_ce, 1u); if (p < 512) candE[p] = n; }
  }
  __syncthreads();
  unsigned ce = s_ce;
  for (int i = tid; i < 512; i += 1024) if (i >= (int)ce) candE[i] = 0x7FFFFFFF;
  __syncthreads();
  // bitonic sort candE ascending (n=512)
  for (int k2 = 2; k2 <= 512; k2 <<= 1)
    for (int j = k2 >> 1; j >= 1; j >>= 1) {
      if (tid < 512) {
        int i = tid, p = i ^ j;
        if (p > i) {
          int a = candE[i], bb = candE[p];
          bool up = ((i & k2) == 0);
          if ((a > bb) == up) { candE[i] = bb; candE[p] = a; }
        }
      }
      __syncthreads();
    }
  int* arr = (int*)hist;   // reuse
  if (tid < KTOP) arr[tid] = (tid < nG) ? candG[tid] : candE[tid - nG];
  __syncthreads();
  // bitonic sort final 256 ascending
  for (int k2 = 2; k2 <= 256; k2 <<= 1)
    for (int j = k2 >> 1; j >= 1; j >>= 1) {
      if (tid < 256) {
        int i = tid, p = i ^ j;
        if (p > i) {
          int a = arr[i], bb = arr[p];
          bool up = ((i & k2) == 0);
          if ((a > bb) == up) { arr[i] = bb; arr[p] = a; }
        }
      }
      __syncthreads();
    }
  if (tid < KTOP) {
    sorti_ws[b * KTOP + tid] = arr[tid];
    out_inds[b * KTOP + tid] = (float)arr[tid];
  }
}

// ============================================================
// Kernel 3: furthest point sampling, bit-exact f32, register-resident.
// 32 WGs/batch. Per-WG LDS reduce -> 1 record/WG (32/batch, 512B-strided).
// Wave 0 of each WG publishes + polls; winner broadcast via LDS.
// Ping-pong banks; tags are t+1 (1..2047): 0x0000 (zeros), 0x5555 (0xAA
// poison) and 0x7FFF (reset) can never match a live tag.
// ============================================================
__global__ __launch_bounds__(FTHR, 1) void k_fps(const float* __restrict__ points,
                                                 unsigned long long* __restrict__ partials,
                                                 int* __restrict__ cross_inds) {
  int b    = blockIdx.x & 7;     // consecutive blockIdx round-robin XCDs -> batch b stays on one XCD
  int wg   = blockIdx.x >> 3;    // 0..31
  int tid  = threadIdx.x;
  int lane = tid & 63;
  int wave = tid >> 6;           // 0..3
  int gthr = wg * FTHR + tid;    // 0..8191 within batch

  __shared__ unsigned long long lred[4];
  __shared__ int lwin;

  const float* pb = points + (size_t)b * NPTS * 3;
  unsigned long long* part = partials + (size_t)b * 2 * NSLOT * RSTRIDE;

  float px[PPT], py[PPT], pz[PPT], dd[PPT];
  #pragma unroll
  for (int i = 0; i < PPT; ++i) {
    int n = gthr + i * FBTHREADS;
    bool v = (n < NPTS);
    px[i] = v ? pb[3 * n + 0] : 0.f;
    py[i] = v ? pb[3 * n + 1] : 0.f;
    pz[i] = v ? pb[3 * n + 2] : 0.f;
    dd[i] = 1e10f;
  }
  if (wg == 0 && tid == 0) cross_inds[b * KFPS] = 0;

  int w = 0;
  for (int t = 0; t < KFPS - 1; ++t) {
    float wx = pb[3 * w + 0];
    float wy = pb[3 * w + 1];
    float wz = pb[3 * w + 2];

    // exact f32 update: d = ((dx*dx + dy*dy) + dz*dz), dist = min(dist, d)
    float bestv = -1.f; int besti = 0x1FFFF;
    #pragma unroll
    for (int i = 0; i < PPT; ++i) {
      int n = gthr + i * FBTHREADS;
      float dx = __fsub_rn(px[i], wx);
      float dy = __fsub_rn(py[i], wy);
      float dz = __fsub_rn(pz[i], wz);
      float s  = __fadd_rn(__fadd_rn(__fmul_rn(dx, dx), __fmul_rn(dy, dy)), __fmul_rn(dz, dz));
      float nd = fminf(dd[i], s);
      dd[i] = nd;
      bool upd = (n < NPTS) && (nd > bestv);   // strict > keeps lowest index on ties
      bestv = upd ? nd : bestv;
      besti = upd ? n : besti;
    }
    // pack (value, ~idx): max => max value, then min index
    unsigned long long key = (bestv >= 0.f)
      ? (((unsigned long long)__float_as_uint(bestv) << 17) |
         (unsigned long long)(0x1FFFFu ^ (unsigned)besti))
      : 0ull;
    #pragma unroll
    for (int off = 32; off >= 1; off >>= 1) {
      unsigned long long o = __shfl_xor(key, off);
      if (o > key) key = o;
    }
    if (lane == 0) lred[wave] = key;
    __syncthreads();

    unsigned tag = (unsigned)t + 1u;
    unsigned long long* bank = part + (size_t)(t & 1) * NSLOT * RSTRIDE;
    if (wave == 0) {
      // publish this WG's record (tagged, self-contained, relaxed agent atomic)
      if (lane == 0) {
        unsigned long long k0 = lred[0], k1 = lred[1], k2 = lred[2], k3 = lred[3];
        if (k1 > k0) k0 = k1;
        if (k3 > k2) k2 = k3;
        if (k2 > k0) k0 = k2;
        unsigned long long rec = ((unsigned long long)tag << TAG_SHIFT) | k0;
        __hip_atomic_store(&bank[(size_t)wg * RSTRIDE], rec,
                           __ATOMIC_RELAXED, __HIP_MEMORY_SCOPE_AGENT);
      }
      // poll all 32 records of this batch (lanes 0..31, one each)
      unsigned long long r = 0;
      unsigned long long* addr = bank + (size_t)(lane & 31) * RSTRIDE;
      int spins = 0;
      for (;;) {
        if (lane < 32)
          r = __hip_atomic_load(addr, __ATOMIC_RELAXED, __HIP_MEMORY_SCOPE_AGENT);
        bool ok = (lane >= 32) || ((unsigned)(r >> TAG_SHIFT) == tag);
        if (__all((int)ok)) break;
        if (++spins > (1 << 15)) break;        // safety: bounded worst case, never hangs
        __builtin_amdgcn_s_sleep(1);
      }
      unsigned long long kk = (lane < 32) ? (r & KEY_MASK) : 0ull;
      #pragma unroll
      for (int off = 32; off >= 1; off >>= 1) {
        unsigned long long o = __shfl_xor(kk, off);
        if (o > kk) kk = o;
      }
      int ww = (int)(0x1FFFFu ^ (unsigned)(kk & IDX_MASK));
      if (ww >= NPTS) ww = 0;                  // safety: never OOB, even on failure
      if (lane == 0) lwin = ww;
    }
    __syncthreads();
    w = lwin;
    if (wg == 0 && tid == 0) cross_inds[b * KFPS + t + 1] = w;
  }
}

// ============================================================
// Kernel 4: gathers (feats_sel, pts_sel, cross_features)
// ============================================================
#define GF4 ((NB * (KTOP + KFPS)) * (ND / 4))   // 589824 float4 gathers
#define GPTS (NB * KTOP * 3)                    // 6144

__global__ void k_gather(const float* __restrict__ pts,
                         const float* __restrict__ feat,
                         const int* __restrict__ sorti,
                         const int* __restrict__ crossi,
                         float* __restrict__ out) {
  int id = blockIdx.x * 256 + threadIdx.x;
  if (id < GF4) {
    int row = id >> 5, c4 = id & 31;
    int b, s; float* dst;
    if (row < NB * KTOP) {
      b = row >> 8;
      s = sorti[row];
      dst = out + OUT_FEATS + (size_t)row * ND;
    } else {
      int r2 = row - NB * KTOP;
      b = r2 >> 11;
      s = crossi[r2];
      dst = out + OUT_CROSS + (size_t)r2 * ND;
    }
    if (s < 0 || s >= NPTS) s = 0;             // safety
    float4 v = ((const float4*)(feat + ((size_t)b * NPTS + (size_t)s) * ND))[c4];
    ((float4*)dst)[c4] = v;
  } else if (id < GF4 + GPTS) {
    int q = id - GF4;
    int row = q / 3, d = q - row * 3;
    int b = row >> 8;
    int s = sorti[row];
    if (s < 0 || s >= NPTS) s = 0;             // safety
    out[OUT_PTS + q] = pts[((size_t)b * NPTS + (size_t)s) * 3 + d];
  }
}

// ============================================================
extern "C" void kernel_launch(void* const* d_in, const int* in_sizes, int n_in,
                              void* d_out, int out_size, void* d_ws, size_t ws_size,
                              hipStream_t stream) {
  const float* cent = (const float*)d_in[0];
  const float* cls  = (const float*)d_in[1];
  const float* pts  = (const float*)d_in[2];
  const float* feat = (const float*)d_in[3];
  float* out = (float*)d_out;

  // big strided record buffer lives in out region 3 (re-inited every call,
  // overwritten by k_gather afterwards) -> d_ws stays at proven 90KB usage
  unsigned long long* partials = (unsigned long long*)(out + OUT_PART);
  int* cross_ws = (int*)((char*)d_ws + WS_CROSS);
  int* sorti_ws = (int*)((char*)d_ws + WS_SORTI);
  float* scores = out + OUT_SCORES;   // scratch inside out region 3 (overwritten later)

  hipLaunchKernelGGL(k_init, dim3((PART_U64 + 255) / 256), dim3(256), 0, stream,
                     partials);
  hipLaunchKernelGGL(k_scores, dim3((NB * NPTS + 255) / 256), dim3(256), 0, stream,
                     cent, cls, scores);
  hipLaunchKernelGGL(k_topk, dim3(NB), dim3(1024), 0, stream,
                     scores, sorti_ws, out + OUT_INDS);
  hipLaunchKernelGGL(k_fps, dim3(NB * FWGS), dim3(FTHR), 0, stream,
                     pts, partials, cross_ws);
  int gtot = GF4 + GPTS;
  hipLaunchKernelGGL(k_gather, dim3((gtot + 255) / 256), dim3(256), 0, stream,
                     pts, feat, sorti_ws, cross_ws, out);
}